// Round 4
// baseline (192.314 us; speedup 1.0000x reference)
//
#include <hip/hip_runtime.h>
#include <math.h>

#define NCLS 80           // background label
#define KDIM 128
#define INV_T 5.0f        // 1/TEMPERATURE
#define AST 136           // A LDS stride (bf16): 128+8 pad -> 2-way banks only
#define BST 68            // B LDS stride (bf16): 64+4 pad -> 2-way banks only

typedef __attribute__((ext_vector_type(4))) float  floatx4;
typedef __attribute__((ext_vector_type(8))) short  short8;

__device__ inline unsigned short f2bf(float x) {      // fp32 -> bf16 RNE
    unsigned int u = __float_as_uint(x);
    u += 0x7fffu + ((u >> 16) & 1u);
    return (unsigned short)(u >> 16);
}
__device__ inline ushort4 pack4(float4 v) {
    ushort4 r; r.x = f2bf(v.x); r.y = f2bf(v.y); r.z = f2bf(v.z); r.w = f2bf(v.w);
    return r;
}

// ---- setup (1 block): zero counters+arrays, compact novel indices, counts ----
__global__ __launch_bounds__(1024) void setup_kernel(
    const int* __restrict__ labels, int M, int B,
    int* __restrict__ novel_idx, int* __restrict__ counters,
    float* __restrict__ zbase /* S1 base: 5*M contiguous floats */)
{
    __shared__ int cnt_n, cfg, cb;
    const int tid  = threadIdx.x;
    const int lane = tid & 63;
    if (tid == 0) { cnt_n = 0; cfg = 0; cb = 0; }

    float4 z = make_float4(0.f, 0.f, 0.f, 0.f);
    float4* b4 = (float4*)zbase;
    const int n4 = (5 * M) >> 2;
    for (int i = tid; i < n4; i += 1024) b4[i] = z;
    __syncthreads();

    int myfg = 0, myb = 0;
    for (int i0 = 0; i0 < M; i0 += 1024) {
        int i = i0 + tid;
        int lab = (i < M) ? labels[i] : NCLS;
        bool fg  = (lab != NCLS);
        bool isb = fg && (lab >= 0) && (lab < B);
        bool isn = fg && !isb;
        unsigned long long m = __ballot(isn);
        int wbase = 0;
        if (lane == 0 && m) wbase = atomicAdd(&cnt_n, __popcll(m));
        wbase = __shfl(wbase, 0);
        if (isn) {
            int pfx = __popcll(m & ((1ull << lane) - 1ull));
            novel_idx[wbase + pfx] = i;
        }
        myfg += fg ? 1 : 0;
        myb  += isb ? 1 : 0;
    }
    #pragma unroll
    for (int off = 32; off; off >>= 1) {
        myfg += __shfl_down(myfg, off);
        myb  += __shfl_down(myb,  off);
    }
    if (lane == 0) { atomicAdd(&cfg, myfg); atomicAdd(&cb, myb); }
    __syncthreads();
    if (tid == 0) {
        counters[0] = cnt_n;   // n_novel
        counters[1] = cfg;     // numel (fg count)
        counters[2] = cb;      // n_base
        counters[3] = 0;       // ticket
    }
}

// ---- MFMA GEMM + fused last-block finalize --------------------------------
// 128x128 out tile / block. Novel tiles -> S1 (sum exp), T1 (sum raw, j!=i).
// Proto tile -> EK (sum exp pk), PKr (sum raw pk), PIv (pk at own label).
// Last block (device ticket) computes the scalar loss.
__global__ __launch_bounds__(256, 3) void gemm_kernel(
    const float* __restrict__ feats, const float* __restrict__ protos,
    const int* __restrict__ labels, const int* __restrict__ novel_idx,
    int* __restrict__ counters, int M, int B, int rtiles,
    float* __restrict__ S1, float* __restrict__ T1,
    float* __restrict__ PKr, float* __restrict__ EK, float* __restrict__ PIv,
    float* __restrict__ out)
{
    __shared__ unsigned short As[128 * AST];   // 34816 B
    __shared__ unsigned short Bs[128 * BST];   // 17408 B
    __shared__ int    nidx[128];
    __shared__ int    rlab[128];
    __shared__ double dred[4];
    __shared__ int    lastflag;

    const int tid = threadIdx.x;
    const int Nn = counters[0];
    const int ntiles = (Nn + 127) >> 7;            // novel col tiles
    const int ct = blockIdx.x / rtiles;            // 0..rtiles (last = proto)
    const int rt = blockIdx.x - ct * rtiles;
    const int row0 = rt * 128;
    const bool active  = (ct <= ntiles);
    const bool isproto = (ct == ntiles);

    if (active) {
        // ---- stage A: 128 rows x 128 k, fp32 -> bf16; plus row labels ----
        const float4* f4 = (const float4*)(feats + (size_t)row0 * KDIM);
        #pragma unroll
        for (int p = 0; p < 16; ++p) {
            int chunk = p * 256 + tid;
            int r = chunk >> 5, kc = chunk & 31;
            *(ushort4*)&As[r * AST + kc * 4] = pack4(f4[r * 32 + kc]);
        }
        if (tid < 128) rlab[tid] = labels[row0 + tid];

        const int wave = tid >> 6, lane = tid & 63;
        const int lr = lane & 15, quad = lane >> 4;
        const int wrow = (wave >> 1) * 64, wcol = (wave & 1) * 64;

        floatx4 acc[4][4];
        #pragma unroll
        for (int r = 0; r < 4; ++r)
            #pragma unroll
            for (int c = 0; c < 4; ++c)
                acc[r][c] = (floatx4){0.f, 0.f, 0.f, 0.f};

        for (int h = 0; h < 2; ++h) {
            if (h) __syncthreads();                // protect Bs reuse
            #pragma unroll
            for (int p = 0; p < 8; ++p) {
                int chunk = p * 256 + tid;
                int r = chunk >> 4, kc = chunk & 15;
                float4 v = make_float4(0.f, 0.f, 0.f, 0.f);
                if (isproto) {
                    if (r < B) v = *(const float4*)(protos + (size_t)r * KDIM + h * 64 + kc * 4);
                } else {
                    int jg = ct * 128 + r;
                    if (jg < Nn)
                        v = *(const float4*)(feats + (size_t)novel_idx[jg] * KDIM + h * 64 + kc * 4);
                }
                *(ushort4*)&Bs[r * BST + kc * 4] = pack4(v);
            }
            if (h == 0 && tid < 128) {
                int nid = -1;
                if (isproto) { if (tid < B) nid = tid; }
                else { int jg = ct * 128 + tid; if (jg < Nn) nid = novel_idx[jg]; }
                nidx[tid] = nid;
            }
            __syncthreads();
            #pragma unroll
            for (int ks = 0; ks < 2; ++ks) {
                short8 a[4], b[4];
                #pragma unroll
                for (int r = 0; r < 4; ++r)
                    a[r] = *(const short8*)&As[(wrow + r * 16 + lr) * AST + h * 64 + ks * 32 + quad * 8];
                #pragma unroll
                for (int c = 0; c < 4; ++c)
                    b[c] = *(const short8*)&Bs[(wcol + c * 16 + lr) * BST + ks * 32 + quad * 8];
                #pragma unroll
                for (int r = 0; r < 4; ++r)
                    #pragma unroll
                    for (int c = 0; c < 4; ++c)
                        acc[r][c] = __builtin_amdgcn_mfma_f32_16x16x32_bf16(
                            a[r], b[c], acc[r][c], 0, 0, 0);
            }
        }

        // ---- epilogue: masked sums + cross-lane reduce + device atomics ----
        int ncol[4];
        #pragma unroll
        for (int c = 0; c < 4; ++c) ncol[c] = nidx[wcol + c * 16 + lr];

        #pragma unroll
        for (int r = 0; r < 4; ++r) {
            #pragma unroll
            for (int reg = 0; reg < 4; ++reg) {
                int lrow = wrow + r * 16 + quad * 4 + reg;   // C/D: row=quad*4+reg
                int irow = row0 + lrow;
                if (isproto) {
                    int lab = rlab[lrow];
                    int sl  = min(max(lab, 0), B - 1);
                    float se = 0.f, sr = 0.f, spi = 0.f;
                    #pragma unroll
                    for (int c = 0; c < 4; ++c) {
                        float sim = acc[r][c][reg] * INV_T;
                        if (ncol[c] >= 0) {
                            se += __expf(sim); sr += sim;
                            if (ncol[c] == sl) spi += sim;
                        }
                    }
                    #pragma unroll
                    for (int off = 1; off < 16; off <<= 1) {
                        se += __shfl_xor(se, off);
                        sr += __shfl_xor(sr, off);
                        spi += __shfl_xor(spi, off);
                    }
                    if (lr == 0) {
                        atomicAdd(&EK[irow], se);
                        atomicAdd(&PKr[irow], sr);
                        atomicAdd(&PIv[irow], spi);
                    }
                } else {
                    float se = 0.f, sr = 0.f;
                    #pragma unroll
                    for (int c = 0; c < 4; ++c) {
                        float sim = acc[r][c][reg] * INV_T;
                        if (ncol[c] >= 0 && ncol[c] != irow) {
                            se += __expf(sim); sr += sim;
                        }
                    }
                    #pragma unroll
                    for (int off = 1; off < 16; off <<= 1) {
                        se += __shfl_xor(se, off);
                        sr += __shfl_xor(sr, off);
                    }
                    if (lr == 0) {
                        atomicAdd(&S1[irow], se);
                        atomicAdd(&T1[irow], sr);
                    }
                }
            }
        }
    }

    // ---- ticket: last arriving block finalizes --------------------------------
    __syncthreads();                 // drains this block's atomics (vmcnt before barrier)
    if (tid == 0) {
        __threadfence();             // release (agent scope)
        int old = atomicAdd(&counters[3], 1);
        lastflag = (old == (int)gridDim.x - 1) ? 1 : 0;
    }
    __syncthreads();
    if (lastflag) {
        __threadfence();             // acquire
        const int numel = counters[1];
        const float cnt = (float)(Nn - 1);
        double part = 0.0;
        for (int i = tid; i < M; i += 256) {
            int lab = labels[i];
            bool fg  = (lab != NCLS);
            bool isb = fg && (lab >= 0) && (lab < B);
            bool isn = fg && !isb;
            if (isn && Nn > 1) {
                float s1 = __hip_atomic_load(&S1[i],  __ATOMIC_RELAXED, __HIP_MEMORY_SCOPE_AGENT);
                float t1 = __hip_atomic_load(&T1[i],  __ATOMIC_RELAXED, __HIP_MEMORY_SCOPE_AGENT);
                float pk = __hip_atomic_load(&PKr[i], __ATOMIC_RELAXED, __HIP_MEMORY_SCOPE_AGENT);
                part += (double)(-(t1 - cnt * logf(s1 + pk)) / cnt);
            } else if (isb) {
                float s1 = __hip_atomic_load(&S1[i],  __ATOMIC_RELAXED, __HIP_MEMORY_SCOPE_AGENT);
                float ek = __hip_atomic_load(&EK[i],  __ATOMIC_RELAXED, __HIP_MEMORY_SCOPE_AGENT);
                float pi = __hip_atomic_load(&PIv[i], __ATOMIC_RELAXED, __HIP_MEMORY_SCOPE_AGENT);
                part += (double)(-(pi - logf(s1 + ek)));
            }
        }
        #pragma unroll
        for (int off = 32; off; off >>= 1) part += __shfl_down(part, off);
        if ((tid & 63) == 0) dred[tid >> 6] = part;
        __syncthreads();
        if (tid == 0)
            out[0] = (float)((dred[0] + dred[1] + dred[2] + dred[3]) / (double)numel);
    }
}

extern "C" void kernel_launch(void* const* d_in, const int* in_sizes, int n_in,
                              void* d_out, int out_size, void* d_ws, size_t ws_size,
                              hipStream_t stream)
{
    const float* feats  = (const float*)d_in[0];
    const int*   labels = (const int*)d_in[1];
    const float* protos = (const float*)d_in[2];
    // d_in[3] proto_labels == arange(B); base membership == (label < B)

    const int M = in_sizes[1];
    const int B = in_sizes[3];

    char* ws = (char*)d_ws;
    int*   counters = (int*)ws;                    // 16 ints (incl. ticket)
    float* S1  = (float*)(ws + 64);                // 5*M contiguous floats
    float* T1  = S1 + M;
    float* PKr = T1 + M;
    float* EK  = PKr + M;
    float* PIv = EK + M;
    int*   novel_idx = (int*)(PIv + M);

    setup_kernel<<<1, 1024, 0, stream>>>(labels, M, B, novel_idx, counters, S1);

    const int rtiles = (M + 127) / 128;            // 64
    const int grid   = rtiles * (rtiles + 1);      // worst-case novel tiles + proto
    gemm_kernel<<<grid, 256, 0, stream>>>(
        feats, protos, labels, novel_idx, counters, M, B, rtiles,
        S1, T1, PKr, EK, PIv, (float*)d_out);
}

// Round 5
// 111.956 us; speedup vs baseline: 1.7178x; 1.7178x over previous
//
#include <hip/hip_runtime.h>
#include <math.h>

#define NCLS 80           // background label
#define KDIM 128
#define INV_T 5.0f        // 1/TEMPERATURE
#define AST 136           // LDS stride (bf16): 128+8 pad; b128 reads -> 2-way only (free)
#define CSPLIT 8          // col-split: blocks per row tile

typedef __attribute__((ext_vector_type(4))) float  floatx4;
typedef __attribute__((ext_vector_type(8))) short  short8;

__device__ inline unsigned short f2bf(float x) {      // fp32 -> bf16 RNE
    unsigned int u = __float_as_uint(x);
    u += 0x7fffu + ((u >> 16) & 1u);
    return (unsigned short)(u >> 16);
}
__device__ inline ushort4 pack4(float4 v) {
    ushort4 r; r.x = f2bf(v.x); r.y = f2bf(v.y); r.z = f2bf(v.z); r.w = f2bf(v.w);
    return r;
}

// ---- setup (32 blocks): zero arrays+out, compact novel indices, counts ------
// counters zeroed by the 64B memset issued before this kernel.
__global__ __launch_bounds__(256) void setup_kernel(
    const int* __restrict__ labels, int M, int B,
    int* __restrict__ novel_idx, int* __restrict__ counters,
    float* __restrict__ zbase /* 4*M contiguous floats: S1,T1,PKr,EK */,
    float* __restrict__ out)
{
    const int gid  = blockIdx.x * 256 + threadIdx.x;
    const int lane = threadIdx.x & 63;
    if (gid == 0) out[0] = 0.f;

    // zero 4*M floats: M=8192 -> 8192 float4 over 8192 threads
    float4* b4 = (float4*)zbase;
    const int n4 = M;                 // (4*M)/4
    for (int i = gid; i < n4; i += gridDim.x * 256)
        b4[i] = make_float4(0.f, 0.f, 0.f, 0.f);

    int lab = (gid < M) ? labels[gid] : NCLS;
    bool fg  = (lab != NCLS);
    bool isb = fg && (lab >= 0) && (lab < B);
    bool isn = fg && !isb;
    unsigned long long m = __ballot(isn);
    int wbase = 0;
    if (lane == 0 && m) wbase = atomicAdd(&counters[0], __popcll(m));
    wbase = __shfl(wbase, 0);
    if (isn) {
        int pfx = __popcll(m & ((1ull << lane) - 1ull));
        novel_idx[wbase + pfx] = gid;
    }
    // counts (per-wave reduce then one atomic)
    int myfg = fg ? 1 : 0, myb = isb ? 1 : 0;
    #pragma unroll
    for (int off = 32; off; off >>= 1) {
        myfg += __shfl_down(myfg, off);
        myb  += __shfl_down(myb,  off);
    }
    if (lane == 0) {
        if (myfg) atomicAdd(&counters[1], myfg);
        if (myb)  atomicAdd(&counters[2], myb);
    }
}

// ---- persistent MFMA GEMM: 512 blocks = 64 row-tiles x 8 col-splits ---------
// Each block stages its A row-tile ONCE (full K, bf16), then loops col tiles
// ct = cs, cs+8, ... ntiles (ct==ntiles is the proto tile).
// Novel tiles -> S1 (sum exp sim, j!=i), T1 (sum raw sim, j!=i).
// Proto tile  -> EK (sum exp pk), PKr (sum raw pk).
__global__ __launch_bounds__(256, 2) void gemm_kernel(
    const float* __restrict__ feats, const float* __restrict__ protos,
    const int* __restrict__ novel_idx, const int* __restrict__ counters,
    int M, int B,
    float* __restrict__ S1, float* __restrict__ T1,
    float* __restrict__ PKr, float* __restrict__ EK)
{
    __shared__ unsigned short As[128 * AST];   // 34816 B
    __shared__ unsigned short Bs[128 * AST];   // 34816 B
    __shared__ int nidx[128];

    const int tid = threadIdx.x;
    const int rt  = blockIdx.x >> 3;
    const int cs  = blockIdx.x & (CSPLIT - 1);
    const int row0 = rt * 128;
    const int Nn = counters[0];
    const int ntiles = (Nn + 127) >> 7;        // ct==ntiles -> proto tile

    // ---- stage A once: 128 rows x 128 k, fp32 -> bf16 ----
    {
        const float4* f4 = (const float4*)(feats + (size_t)row0 * KDIM);
        #pragma unroll
        for (int p = 0; p < 16; ++p) {
            int chunk = p * 256 + tid;         // 4096 chunks of 4 floats
            int r = chunk >> 5, kc = chunk & 31;
            *(ushort4*)&As[r * AST + kc * 4] = pack4(f4[r * 32 + kc]);
        }
    }

    const int wave = tid >> 6, lane = tid & 63;
    const int lr = lane & 15, quad = lane >> 4;
    const int wrow = (wave >> 1) * 64, wcol = (wave & 1) * 64;

    for (int ct = cs; ct <= ntiles; ct += CSPLIT) {
        const bool isproto = (ct == ntiles);
        __syncthreads();                       // prev iter's reads of Bs/nidx done (also A visible)
        // ---- stage B: 128 cols x 128 k (gathered novel rows / protos) ----
        #pragma unroll
        for (int p = 0; p < 16; ++p) {
            int chunk = p * 256 + tid;
            int r = chunk >> 5, kc = chunk & 31;
            float4 v = make_float4(0.f, 0.f, 0.f, 0.f);
            if (isproto) {
                if (r < B) v = *(const float4*)(protos + (size_t)r * KDIM + kc * 4);
            } else {
                int jg = ct * 128 + r;
                if (jg < Nn)
                    v = *(const float4*)(feats + (size_t)novel_idx[jg] * KDIM + kc * 4);
            }
            *(ushort4*)&Bs[r * AST + kc * 4] = pack4(v);
        }
        if (tid < 128) {
            int nid = -1;
            if (isproto) { if (tid < B) nid = tid; }
            else { int jg = ct * 128 + tid; if (jg < Nn) nid = novel_idx[jg]; }
            nidx[tid] = nid;
        }
        __syncthreads();

        floatx4 acc[4][4];
        #pragma unroll
        for (int r = 0; r < 4; ++r)
            #pragma unroll
            for (int c = 0; c < 4; ++c)
                acc[r][c] = (floatx4){0.f, 0.f, 0.f, 0.f};

        #pragma unroll
        for (int ks = 0; ks < 4; ++ks) {
            short8 a[4], b[4];
            #pragma unroll
            for (int r = 0; r < 4; ++r)
                a[r] = *(const short8*)&As[(wrow + r * 16 + lr) * AST + ks * 32 + quad * 8];
            #pragma unroll
            for (int c = 0; c < 4; ++c)
                b[c] = *(const short8*)&Bs[(wcol + c * 16 + lr) * AST + ks * 32 + quad * 8];
            #pragma unroll
            for (int r = 0; r < 4; ++r)
                #pragma unroll
                for (int c = 0; c < 4; ++c)
                    acc[r][c] = __builtin_amdgcn_mfma_f32_16x16x32_bf16(
                        a[r], b[c], acc[r][c], 0, 0, 0);
        }

        // ---- epilogue: masked sums + 16-lane reduce + device atomics ----
        int ncol[4];
        #pragma unroll
        for (int c = 0; c < 4; ++c) ncol[c] = nidx[wcol + c * 16 + lr];

        #pragma unroll
        for (int r = 0; r < 4; ++r) {
            #pragma unroll
            for (int reg = 0; reg < 4; ++reg) {
                int irow = row0 + wrow + r * 16 + quad * 4 + reg;  // C/D: row=quad*4+reg
                float se = 0.f, sr = 0.f;
                #pragma unroll
                for (int c = 0; c < 4; ++c) {
                    float sim = acc[r][c][reg] * INV_T;
                    bool valid = (ncol[c] >= 0) && (isproto || ncol[c] != irow);
                    if (valid) { se += __expf(sim); sr += sim; }
                }
                #pragma unroll
                for (int off = 1; off < 16; off <<= 1) {
                    se += __shfl_xor(se, off);
                    sr += __shfl_xor(sr, off);
                }
                if (lr == 0) {
                    if (isproto) { atomicAdd(&EK[irow], se); atomicAdd(&PKr[irow], sr); }
                    else         { atomicAdd(&S1[irow], se); atomicAdd(&T1[irow], sr); }
                }
            }
        }
    }
}

// ---- finalize: per-row losses (pi exact in fp32) -> scalar ------------------
__global__ __launch_bounds__(256) void finalize_kernel(
    const float* __restrict__ feats, const float* __restrict__ protos,
    const int* __restrict__ labels,
    const float* __restrict__ S1, const float* __restrict__ T1,
    const float* __restrict__ PKr, const float* __restrict__ EK,
    const int* __restrict__ counters, int M, int B, float* __restrict__ out)
{
    __shared__ float part[16];
    const int tid  = threadIdx.x;
    const int rloc = tid >> 4;
    const int q    = tid & 15;
    const int row  = blockIdx.x * 16 + rloc;
    const int rs   = min(row, M - 1);

    const int Nn = counters[0], numel = counters[1];

    int lab = labels[rs];
    bool fg  = (lab != NCLS);
    bool isb = fg && (lab >= 0) && (lab < B);
    bool isn = fg && !isb;
    int  sl  = min(max(lab, 0), B - 1);

    // exact fp32 dot f_row . protos[sl] (16 lanes x 8 elems)
    float d = 0.f;
    #pragma unroll
    for (int j = 0; j < 8; ++j) {
        int k = q + j * 16;
        d += feats[(size_t)rs * KDIM + k] * protos[(size_t)sl * KDIM + k];
    }
    #pragma unroll
    for (int off = 1; off < 16; off <<= 1) d += __shfl_xor(d, off);

    if (q == 0) {
        float loss = 0.f;
        if (row < M) {
            if (isn && Nn > 1) {
                float cnt = (float)(Nn - 1);
                float dn  = S1[rs] + PKr[rs];
                loss = -(T1[rs] - cnt * logf(dn)) / cnt;
            } else if (isb) {
                float pi = d * INV_T;
                float db = S1[rs] + EK[rs];
                loss = -(pi - logf(db));
            }
        }
        part[rloc] = loss;
    }
    __syncthreads();
    if (tid == 0) {
        float s = 0.f;
        #pragma unroll
        for (int r = 0; r < 16; ++r) s += part[r];
        atomicAdd(out, s / (float)numel);
    }
}

extern "C" void kernel_launch(void* const* d_in, const int* in_sizes, int n_in,
                              void* d_out, int out_size, void* d_ws, size_t ws_size,
                              hipStream_t stream)
{
    const float* feats  = (const float*)d_in[0];
    const int*   labels = (const int*)d_in[1];
    const float* protos = (const float*)d_in[2];
    // d_in[3] proto_labels == arange(B); base membership == (label < B)

    const int M = in_sizes[1];
    const int B = in_sizes[3];

    char* ws = (char*)d_ws;
    int*   counters = (int*)ws;                   // 16 ints
    float* S1  = (float*)(ws + 64);               // 4*M contiguous floats
    float* T1  = S1 + M;
    float* PKr = T1 + M;
    float* EK  = PKr + M;
    int*   novel_idx = (int*)(EK + M);

    hipMemsetAsync(counters, 0, 64, stream);

    setup_kernel<<<(M + 255) / 256, 256, 0, stream>>>(
        labels, M, B, novel_idx, counters, S1, (float*)d_out);

    const int rtiles = (M + 127) / 128;           // 64
    gemm_kernel<<<rtiles * CSPLIT, 256, 0, stream>>>(
        feats, protos, novel_idx, counters, M, B, S1, T1, PKr, EK);

    finalize_kernel<<<(M + 15) / 16, 256, 0, stream>>>(
        feats, protos, labels, S1, T1, PKr, EK, counters, M, B, (float*)d_out);
}